// Round 7
// baseline (144.100 us; speedup 1.0000x reference)
//
#include <hip/hip_runtime.h>

#define TT_S 6
#define TT_H 8
#define TT_FF 16
#define SEQ_PER_BLK 64
#define BLK 384                 /* 64 seqs * 6 tokens = 6 waves */
#define KV_STRIDE_U 52          /* uints per seq; 52 mod 32 = 20 -> seq windows tile banks, <=2-way (free) */

/* packed-fp16 weight layout in d_ws (uint offsets) */
#define WQH  0
#define WKH  32
#define WVH  64
#define WOH  96
#define W1H  128
#define W2H  192
#define POSH 256

typedef __fp16   h2_t  __attribute__((ext_vector_type(2)));
typedef __fp16   h8_t  __attribute__((ext_vector_type(8)));
typedef _Float16 f16x2 __attribute__((ext_vector_type(2)));

__device__ __forceinline__ unsigned pk2(float a, float b) {
  h2_t h = __builtin_amdgcn_cvt_pkrtz(a, b);
  return __builtin_bit_cast(unsigned, h);
}
__device__ __forceinline__ h2_t pk2h(float a, float b) {
  return __builtin_amdgcn_cvt_pkrtz(a, b);
}
__device__ __forceinline__ h2_t bch(unsigned u) {
  return __builtin_bit_cast(h2_t, u);
}

#if __has_builtin(__builtin_amdgcn_fdot2)
__device__ __forceinline__ float dot2f(h2_t a, h2_t b, float c) {
  return __builtin_amdgcn_fdot2(__builtin_bit_cast(f16x2, a),
                                __builtin_bit_cast(f16x2, b), c, false);
}
#else
__device__ __forceinline__ float dot2f(h2_t a, h2_t b, float c) {
  return fmaf((float)a[0], (float)b[0], fmaf((float)a[1], (float)b[1], c));
}
#endif

/* ---- prep: pack weights + pos_emb to fp16 pairs in ws (runs every call) ---- */
__global__ void tt_prep(const float* __restrict__ Wq, const float* __restrict__ Wk,
                        const float* __restrict__ Wv, const float* __restrict__ Wo,
                        const float* __restrict__ W1, const float* __restrict__ W2,
                        const float* __restrict__ pos, unsigned* __restrict__ ws)
{
  const int i = threadIdx.x;  // 128 threads
  if (i < 128) {
    const float* Wm = (i < 32) ? Wq : (i < 64) ? Wk : (i < 96) ? Wv : Wo;
    const int p = i & 31;
    ws[i] = pk2(Wm[2*p], Wm[2*p+1]);
  }
  if (i < 64) {
    ws[W1H + i] = pk2(W1[2*i], W1[2*i+1]);
    ws[W2H + i] = pk2(W2[2*i], W2[2*i+1]);
  }
  if (i < 24) ws[POSH + i] = pk2(pos[2*i], pos[2*i+1]);
}

__global__ __launch_bounds__(BLK, 6) void tt_fused(
    const int* __restrict__ ids,
    const float* __restrict__ tok_emb,
    const unsigned* __restrict__ wsu,
    const float* __restrict__ bq, const float* __restrict__ bk,
    const float* __restrict__ bv, const float* __restrict__ bo,
    const float* __restrict__ b1, const float* __restrict__ b2,
    const float* __restrict__ g1, const float* __restrict__ be1,
    const float* __restrict__ g2, const float* __restrict__ be2,
    float* __restrict__ out, int B)
{
  __shared__ __align__(16) unsigned s_kv[SEQ_PER_BLK * KV_STRIDE_U];
  __shared__ __align__(16) unsigned s_tok[400];   // 100 rows x 4 uints (8 f16)

  const int tid = threadIdx.x;
  for (int i = tid; i < 400; i += BLK) {
    float2 tv = ((const float2*)tok_emb)[i];
    s_tok[i] = pk2(tv.x, tv.y);
  }
  __syncthreads();

  const int s_loc = tid / TT_S;
  const int t     = tid - s_loc * TT_S;
  const int seq_g = blockIdx.x * SEQ_PER_BLK + s_loc;
  const bool valid = (seq_g < B);
  const size_t gidx = (size_t)blockIdx.x * BLK + tid;
  const int id = valid ? ids[gidx] : 0;

  // ---- x row = tok(f16) + pos(f16), packed pairs ----
  uint4 tw = ((const uint4*)s_tok)[id];
  uint4 pw = ((const uint4*)(wsu + POSH))[t];
  h2_t xs0 = bch(tw.x) + bch(pw.x);
  h2_t xs1 = bch(tw.y) + bch(pw.y);
  h2_t xs2 = bch(tw.z) + bch(pw.z);
  h2_t xs3 = bch(tw.w) + bch(pw.w);

  // f32 copy for the residual
  float xf[TT_H];
  xf[0] = (float)xs0[0]; xf[1] = (float)xs0[1];
  xf[2] = (float)xs1[0]; xf[3] = (float)xs1[1];
  xf[4] = (float)xs2[0]; xf[5] = (float)xs2[1];
  xf[6] = (float)xs3[0]; xf[7] = (float)xs3[1];

  // ---- k,v for OWN token via dot2; pack -> LDS ----
  {
    float kr[TT_H], vr[TT_H];
    #pragma unroll
    for (int i = 0; i < TT_H; ++i) {
      float ak = bk[i], av = bv[i];
      ak = dot2f(xs0, bch(wsu[WKH + i*4 + 0]), ak);
      ak = dot2f(xs1, bch(wsu[WKH + i*4 + 1]), ak);
      ak = dot2f(xs2, bch(wsu[WKH + i*4 + 2]), ak);
      ak = dot2f(xs3, bch(wsu[WKH + i*4 + 3]), ak);
      av = dot2f(xs0, bch(wsu[WVH + i*4 + 0]), av);
      av = dot2f(xs1, bch(wsu[WVH + i*4 + 1]), av);
      av = dot2f(xs2, bch(wsu[WVH + i*4 + 2]), av);
      av = dot2f(xs3, bch(wsu[WVH + i*4 + 3]), av);
      kr[i] = ak; vr[i] = av;
    }
    unsigned* kvp = s_kv + s_loc * KV_STRIDE_U + t * 8;
    uint4 w0, w1;
    w0.x = pk2(kr[0], kr[1]); w0.y = pk2(kr[2], kr[3]);
    w0.z = pk2(kr[4], kr[5]); w0.w = pk2(kr[6], kr[7]);
    w1.x = pk2(vr[0], vr[1]); w1.y = pk2(vr[2], vr[3]);
    w1.z = pk2(vr[4], vr[5]); w1.w = pk2(vr[6], vr[7]);
    ((uint4*)kvp)[0] = w0;
    ((uint4*)kvp)[1] = w1;
  }
  __syncthreads();

  // ---- q row via dot2; fold scale 1/sqrt(HD)*log2(e) = 0.7213475 before packing ----
  h2_t qh[4];
  #pragma unroll
  for (int i = 0; i < 4; ++i) {
    float a0 = bq[2*i], a1 = bq[2*i+1];
    a0 = dot2f(xs0, bch(wsu[WQH + (2*i)*4 + 0]), a0);
    a0 = dot2f(xs1, bch(wsu[WQH + (2*i)*4 + 1]), a0);
    a0 = dot2f(xs2, bch(wsu[WQH + (2*i)*4 + 2]), a0);
    a0 = dot2f(xs3, bch(wsu[WQH + (2*i)*4 + 3]), a0);
    a1 = dot2f(xs0, bch(wsu[WQH + (2*i+1)*4 + 0]), a1);
    a1 = dot2f(xs1, bch(wsu[WQH + (2*i+1)*4 + 1]), a1);
    a1 = dot2f(xs2, bch(wsu[WQH + (2*i+1)*4 + 2]), a1);
    a1 = dot2f(xs3, bch(wsu[WQH + (2*i+1)*4 + 3]), a1);
    qh[i] = pk2h(a0 * 0.7213475204f, a1 * 0.7213475204f);
  }

  // ---- attention: exp2(q'.k) accumulated online; V via fma_mix ----
  float acc[TT_H] = {0.f,0.f,0.f,0.f,0.f,0.f,0.f,0.f};
  float sum0 = 0.f, sum1 = 0.f;
  const uint4* kvb = (const uint4*)(s_kv + s_loc * KV_STRIDE_U);
  #pragma unroll
  for (int t2 = 0; t2 < TT_S; ++t2) {
    uint4 kw = kvb[t2*2];
    uint4 vw = kvb[t2*2+1];
    float d0 = dot2f(qh[0], bch(kw.x), 0.f);
    d0 = dot2f(qh[1], bch(kw.y), d0);
    float d1 = dot2f(qh[2], bch(kw.z), 0.f);
    d1 = dot2f(qh[3], bch(kw.w), d1);
    float e0 = __builtin_amdgcn_exp2f(d0);
    float e1 = __builtin_amdgcn_exp2f(d1);
    sum0 += e0; sum1 += e1;
    h8_t vh = __builtin_bit_cast(h8_t, vw);
    acc[0] = fmaf(e0, (float)vh[0], acc[0]);
    acc[1] = fmaf(e0, (float)vh[1], acc[1]);
    acc[2] = fmaf(e0, (float)vh[2], acc[2]);
    acc[3] = fmaf(e0, (float)vh[3], acc[3]);
    acc[4] = fmaf(e1, (float)vh[4], acc[4]);
    acc[5] = fmaf(e1, (float)vh[5], acc[5]);
    acc[6] = fmaf(e1, (float)vh[6], acc[6]);
    acc[7] = fmaf(e1, (float)vh[7], acc[7]);
  }
  h2_t ah[4];
  {
    float inv0 = __builtin_amdgcn_rcpf(sum0);
    float inv1 = __builtin_amdgcn_rcpf(sum1);
    ah[0] = pk2h(acc[0]*inv0, acc[1]*inv0);
    ah[1] = pk2h(acc[2]*inv0, acc[3]*inv0);
    ah[2] = pk2h(acc[4]*inv1, acc[5]*inv1);
    ah[3] = pk2h(acc[6]*inv1, acc[7]*inv1);
  }

  // ---- o = attn @ Wo.T + bo (dot2); residual; LN1 ----
  float r[TT_H];
  float mu = 0.f;
  #pragma unroll
  for (int i = 0; i < TT_H; ++i) {
    float o = bo[i];
    o = dot2f(ah[0], bch(wsu[WOH + i*4 + 0]), o);
    o = dot2f(ah[1], bch(wsu[WOH + i*4 + 1]), o);
    o = dot2f(ah[2], bch(wsu[WOH + i*4 + 2]), o);
    o = dot2f(ah[3], bch(wsu[WOH + i*4 + 3]), o);
    r[i] = xf[i] + o;
    mu += r[i];
  }
  mu *= 0.125f;
  float var = 0.f;
  #pragma unroll
  for (int i = 0; i < TT_H; ++i) { float d = r[i] - mu; var = fmaf(d, d, var); }
  float rin = __builtin_amdgcn_rsqf(fmaf(var, 0.125f, 1e-5f));
  float mc = mu * rin;
  float hr[TT_H];
  #pragma unroll
  for (int i = 0; i < TT_H; ++i)
    hr[i] = fmaf(fmaf(r[i], rin, -mc), g1[i], be1[i]);
  h2_t hh[4];
  hh[0] = pk2h(hr[0], hr[1]);
  hh[1] = pk2h(hr[2], hr[3]);
  hh[2] = pk2h(hr[4], hr[5]);
  hh[3] = pk2h(hr[6], hr[7]);

  // ---- ffn1 (dot2): gelu(u) = u - u*rcp(e+1), e = 2^(u*(2.3022072 + 0.1029432*u^2)) ----
  h2_t fh[8];
  #pragma unroll
  for (int f = 0; f < TT_FF; f += 2) {
    float u0 = b1[f], u1 = b1[f+1];
    u0 = dot2f(hh[0], bch(wsu[W1H + f*4 + 0]), u0);
    u0 = dot2f(hh[1], bch(wsu[W1H + f*4 + 1]), u0);
    u0 = dot2f(hh[2], bch(wsu[W1H + f*4 + 2]), u0);
    u0 = dot2f(hh[3], bch(wsu[W1H + f*4 + 3]), u0);
    u1 = dot2f(hh[0], bch(wsu[W1H + f*4 + 4]), u1);
    u1 = dot2f(hh[1], bch(wsu[W1H + f*4 + 5]), u1);
    u1 = dot2f(hh[2], bch(wsu[W1H + f*4 + 6]), u1);
    u1 = dot2f(hh[3], bch(wsu[W1H + f*4 + 7]), u1);
    float e0 = __builtin_amdgcn_exp2f(u0 * fmaf(0.1029432f, u0*u0, 2.3022072f));
    float e1 = __builtin_amdgcn_exp2f(u1 * fmaf(0.1029432f, u1*u1, 2.3022072f));
    float g0 = fmaf(-u0, __builtin_amdgcn_rcpf(e0 + 1.0f), u0);
    float g1v = fmaf(-u1, __builtin_amdgcn_rcpf(e1 + 1.0f), u1);
    fh[f>>1] = pk2h(g0, g1v);
  }

  // ---- y = f1 @ W2.T + b2 (dot2); residual; LN2; store ----
  float r2[TT_H];
  float mu2 = 0.f;
  #pragma unroll
  for (int i = 0; i < TT_H; ++i) {
    float y = b2[i];
    y = dot2f(fh[0], bch(wsu[W2H + i*8 + 0]), y);
    y = dot2f(fh[1], bch(wsu[W2H + i*8 + 1]), y);
    y = dot2f(fh[2], bch(wsu[W2H + i*8 + 2]), y);
    y = dot2f(fh[3], bch(wsu[W2H + i*8 + 3]), y);
    y = dot2f(fh[4], bch(wsu[W2H + i*8 + 4]), y);
    y = dot2f(fh[5], bch(wsu[W2H + i*8 + 5]), y);
    y = dot2f(fh[6], bch(wsu[W2H + i*8 + 6]), y);
    y = dot2f(fh[7], bch(wsu[W2H + i*8 + 7]), y);
    r2[i] = hr[i] + y;
    mu2 += r2[i];
  }
  mu2 *= 0.125f;
  float var2 = 0.f;
  #pragma unroll
  for (int i = 0; i < TT_H; ++i) { float d = r2[i] - mu2; var2 = fmaf(d, d, var2); }
  float rin2 = __builtin_amdgcn_rsqf(fmaf(var2, 0.125f, 1e-5f));
  float mc2 = mu2 * rin2;

  if (valid) {
    float res[TT_H];
    #pragma unroll
    for (int i = 0; i < TT_H; ++i)
      res[i] = fmaf(fmaf(r2[i], rin2, -mc2), g2[i], be2[i]);
    float* op = out + gidx * TT_H;
    float4 v0; v0.x = res[0]; v0.y = res[1]; v0.z = res[2]; v0.w = res[3];
    float4 v1; v1.x = res[4]; v1.y = res[5]; v1.z = res[6]; v1.w = res[7];
    ((float4*)op)[0] = v0;
    ((float4*)op)[1] = v1;
  }
}

extern "C" void kernel_launch(void* const* d_in, const int* in_sizes, int n_in,
                              void* d_out, int out_size, void* d_ws, size_t ws_size,
                              hipStream_t stream) {
  const int*   ids = (const int*)  d_in[0];
  const float* tok = (const float*)d_in[1];
  const float* pos = (const float*)d_in[2];
  const float* Wq  = (const float*)d_in[3];
  const float* bq  = (const float*)d_in[4];
  const float* Wk  = (const float*)d_in[5];
  const float* bk  = (const float*)d_in[6];
  const float* Wv  = (const float*)d_in[7];
  const float* bv  = (const float*)d_in[8];
  const float* Wo  = (const float*)d_in[9];
  const float* bo  = (const float*)d_in[10];
  const float* W1  = (const float*)d_in[11];
  const float* b1  = (const float*)d_in[12];
  const float* W2  = (const float*)d_in[13];
  const float* b2  = (const float*)d_in[14];
  const float* g1  = (const float*)d_in[15];
  const float* be1 = (const float*)d_in[16];
  const float* g2  = (const float*)d_in[17];
  const float* be2 = (const float*)d_in[18];
  float* out = (float*)d_out;
  unsigned* ws = (unsigned*)d_ws;

  hipLaunchKernelGGL(tt_prep, dim3(1), dim3(128), 0, stream,
                     Wq, Wk, Wv, Wo, W1, W2, pos, ws);

  const int B = in_sizes[0] / TT_S;
  const int grid = (B + SEQ_PER_BLK - 1) / SEQ_PER_BLK;
  hipLaunchKernelGGL(tt_fused, dim3(grid), dim3(BLK), 0, stream,
                     ids, tok, ws, bq, bk, bv, bo, b1, b2,
                     g1, be1, g2, be2, out, B);
}

// Round 8
// 139.490 us; speedup vs baseline: 1.0330x; 1.0330x over previous
//
#include <hip/hip_runtime.h>

#define TT_S 6
#define TT_H 8
#define TT_FF 16
#define WAVES_PER_BLK 4
#define BLK (WAVES_PER_BLK * 64)      /* 256 threads */
#define SEQ_PER_WAVE 10               /* 60 active lanes, 4 idle */
#define SEQ_PER_BLK (WAVES_PER_BLK * SEQ_PER_WAVE)  /* 40 */
#define SEQ_STRIDE_U 52               /* 48 data uints + 4 pad; 52*4 mod 32 banks -> <=2-way */
#define WAVE_STRIDE_U (SEQ_PER_WAVE * SEQ_STRIDE_U + 8)  /* 528 */

/* packed-fp16 layout in d_ws (uint offsets) */
#define WQH  0
#define WKH  32
#define WVH  64
#define WOH  96
#define W1H  128
#define W2H  192
#define POSH 256
#define TOKH 288    /* 400 uints */

typedef __fp16   h2_t  __attribute__((ext_vector_type(2)));
typedef __fp16   h8_t  __attribute__((ext_vector_type(8)));
typedef _Float16 f16x2 __attribute__((ext_vector_type(2)));

__device__ __forceinline__ unsigned pk2(float a, float b) {
  h2_t h = __builtin_amdgcn_cvt_pkrtz(a, b);
  return __builtin_bit_cast(unsigned, h);
}
__device__ __forceinline__ h2_t pk2h(float a, float b) {
  return __builtin_amdgcn_cvt_pkrtz(a, b);
}
__device__ __forceinline__ h2_t bch(unsigned u) {
  return __builtin_bit_cast(h2_t, u);
}

#if __has_builtin(__builtin_amdgcn_fdot2)
__device__ __forceinline__ float dot2f(h2_t a, h2_t b, float c) {
  return __builtin_amdgcn_fdot2(__builtin_bit_cast(f16x2, a),
                                __builtin_bit_cast(f16x2, b), c, false);
}
#else
__device__ __forceinline__ float dot2f(h2_t a, h2_t b, float c) {
  return fmaf((float)a[0], (float)b[0], fmaf((float)a[1], (float)b[1], c));
}
#endif

/* ---- prep: pack weights + pos + tok_emb to fp16 pairs in ws ---- */
__global__ void tt_prep(const float* __restrict__ Wq, const float* __restrict__ Wk,
                        const float* __restrict__ Wv, const float* __restrict__ Wo,
                        const float* __restrict__ W1, const float* __restrict__ W2,
                        const float* __restrict__ pos, const float* __restrict__ tok,
                        unsigned* __restrict__ ws)
{
  const int i = threadIdx.x;  // 512 threads
  if (i < 128) {
    const float* Wm = (i < 32) ? Wq : (i < 64) ? Wk : (i < 96) ? Wv : Wo;
    const int p = i & 31;
    ws[i] = pk2(Wm[2*p], Wm[2*p+1]);
  }
  if (i < 64) {
    ws[W1H + i] = pk2(W1[2*i], W1[2*i+1]);
    ws[W2H + i] = pk2(W2[2*i], W2[2*i+1]);
  }
  if (i < 24) ws[POSH + i] = pk2(pos[2*i], pos[2*i+1]);
  if (i < 400) ws[TOKH + i] = pk2(tok[2*i], tok[2*i+1]);
}

__global__ __launch_bounds__(BLK, 8) void tt_fused(
    const int* __restrict__ ids,
    const unsigned* __restrict__ wsu,
    const float* __restrict__ bq, const float* __restrict__ bk,
    const float* __restrict__ bv, const float* __restrict__ bo,
    const float* __restrict__ b1, const float* __restrict__ b2,
    const float* __restrict__ g1, const float* __restrict__ be1,
    const float* __restrict__ g2, const float* __restrict__ be2,
    float* __restrict__ out, int B)
{
  // Per-wave KV exchange region. NO __syncthreads anywhere: sequences are
  // wave-local, and a wave's DS ops execute in program order.
  __shared__ __align__(16) unsigned s_kv[WAVES_PER_BLK * WAVE_STRIDE_U];

  const int tid = threadIdx.x;
  const int wv  = tid >> 6;
  const int ln  = tid & 63;
  const int slr = ln / 6;                 // 0..10
  const int t   = ln - slr * 6;           // 0..5 for active lanes
  const int seq_g = blockIdx.x * SEQ_PER_BLK + wv * SEQ_PER_WAVE + slr;
  if (ln >= 60 || seq_g >= B) return;     // legal: no barriers below

  const size_t gidx = (size_t)seq_g * TT_S + t;   // == blk_base*6 + ln for full blocks: coalesced
  const int id = ids[gidx];

  // ---- x row = tok(f16, global/L1) + pos(f16), packed pairs ----
  uint4 tw = ((const uint4*)(wsu + TOKH))[id];
  uint4 pw = ((const uint4*)(wsu + POSH))[t];
  h2_t xs0 = bch(tw.x) + bch(pw.x);
  h2_t xs1 = bch(tw.y) + bch(pw.y);
  h2_t xs2 = bch(tw.z) + bch(pw.z);
  h2_t xs3 = bch(tw.w) + bch(pw.w);

  float xf[TT_H];
  xf[0] = (float)xs0[0]; xf[1] = (float)xs0[1];
  xf[2] = (float)xs1[0]; xf[3] = (float)xs1[1];
  xf[4] = (float)xs2[0]; xf[5] = (float)xs2[1];
  xf[6] = (float)xs3[0]; xf[7] = (float)xs3[1];

  unsigned* kvbase = s_kv + wv * WAVE_STRIDE_U + slr * SEQ_STRIDE_U;

  // ---- k,v for OWN token via dot2; pack -> wave-local LDS ----
  {
    float kr[TT_H], vr[TT_H];
    #pragma unroll
    for (int i = 0; i < TT_H; ++i) {
      float ak = bk[i], av = bv[i];
      ak = dot2f(xs0, bch(wsu[WKH + i*4 + 0]), ak);
      ak = dot2f(xs1, bch(wsu[WKH + i*4 + 1]), ak);
      ak = dot2f(xs2, bch(wsu[WKH + i*4 + 2]), ak);
      ak = dot2f(xs3, bch(wsu[WKH + i*4 + 3]), ak);
      av = dot2f(xs0, bch(wsu[WVH + i*4 + 0]), av);
      av = dot2f(xs1, bch(wsu[WVH + i*4 + 1]), av);
      av = dot2f(xs2, bch(wsu[WVH + i*4 + 2]), av);
      av = dot2f(xs3, bch(wsu[WVH + i*4 + 3]), av);
      kr[i] = ak; vr[i] = av;
    }
    unsigned* kvp = kvbase + t * 8;
    uint4 w0, w1;
    w0.x = pk2(kr[0], kr[1]); w0.y = pk2(kr[2], kr[3]);
    w0.z = pk2(kr[4], kr[5]); w0.w = pk2(kr[6], kr[7]);
    w1.x = pk2(vr[0], vr[1]); w1.y = pk2(vr[2], vr[3]);
    w1.z = pk2(vr[4], vr[5]); w1.w = pk2(vr[6], vr[7]);
    ((uint4*)kvp)[0] = w0;
    ((uint4*)kvp)[1] = w1;
  }
  __builtin_amdgcn_wave_barrier();   // scheduling fence only; same-wave DS ops are ordered

  // ---- q row via dot2; fold 1/sqrt(HD)*log2(e) = 0.7213475 before packing ----
  h2_t qh[4];
  #pragma unroll
  for (int i = 0; i < 4; ++i) {
    float a0 = bq[2*i], a1 = bq[2*i+1];
    a0 = dot2f(xs0, bch(wsu[WQH + (2*i)*4 + 0]), a0);
    a0 = dot2f(xs1, bch(wsu[WQH + (2*i)*4 + 1]), a0);
    a0 = dot2f(xs2, bch(wsu[WQH + (2*i)*4 + 2]), a0);
    a0 = dot2f(xs3, bch(wsu[WQH + (2*i)*4 + 3]), a0);
    a1 = dot2f(xs0, bch(wsu[WQH + (2*i+1)*4 + 0]), a1);
    a1 = dot2f(xs1, bch(wsu[WQH + (2*i+1)*4 + 1]), a1);
    a1 = dot2f(xs2, bch(wsu[WQH + (2*i+1)*4 + 2]), a1);
    a1 = dot2f(xs3, bch(wsu[WQH + (2*i+1)*4 + 3]), a1);
    qh[i] = pk2h(a0 * 0.7213475204f, a1 * 0.7213475204f);
  }

  // ---- attention over the seq's 6 K/V rows (broadcast reads within seq) ----
  float acc[TT_H] = {0.f,0.f,0.f,0.f,0.f,0.f,0.f,0.f};
  float sum0 = 0.f, sum1 = 0.f;
  const uint4* kvb = (const uint4*)kvbase;
  #pragma unroll
  for (int t2 = 0; t2 < TT_S; ++t2) {
    uint4 kw = kvb[t2*2];
    uint4 vw = kvb[t2*2+1];
    float d0 = dot2f(qh[0], bch(kw.x), 0.f);
    d0 = dot2f(qh[1], bch(kw.y), d0);
    float d1 = dot2f(qh[2], bch(kw.z), 0.f);
    d1 = dot2f(qh[3], bch(kw.w), d1);
    float e0 = __builtin_amdgcn_exp2f(d0);
    float e1 = __builtin_amdgcn_exp2f(d1);
    sum0 += e0; sum1 += e1;
    h8_t vh = __builtin_bit_cast(h8_t, vw);
    acc[0] = fmaf(e0, (float)vh[0], acc[0]);
    acc[1] = fmaf(e0, (float)vh[1], acc[1]);
    acc[2] = fmaf(e0, (float)vh[2], acc[2]);
    acc[3] = fmaf(e0, (float)vh[3], acc[3]);
    acc[4] = fmaf(e1, (float)vh[4], acc[4]);
    acc[5] = fmaf(e1, (float)vh[5], acc[5]);
    acc[6] = fmaf(e1, (float)vh[6], acc[6]);
    acc[7] = fmaf(e1, (float)vh[7], acc[7]);
  }
  h2_t ah[4];
  {
    float inv0 = __builtin_amdgcn_rcpf(sum0);
    float inv1 = __builtin_amdgcn_rcpf(sum1);
    ah[0] = pk2h(acc[0]*inv0, acc[1]*inv0);
    ah[1] = pk2h(acc[2]*inv0, acc[3]*inv0);
    ah[2] = pk2h(acc[4]*inv1, acc[5]*inv1);
    ah[3] = pk2h(acc[6]*inv1, acc[7]*inv1);
  }

  // ---- o = attn @ Wo.T + bo; residual; LN1 ----
  float r[TT_H];
  float mu = 0.f;
  #pragma unroll
  for (int i = 0; i < TT_H; ++i) {
    float o = bo[i];
    o = dot2f(ah[0], bch(wsu[WOH + i*4 + 0]), o);
    o = dot2f(ah[1], bch(wsu[WOH + i*4 + 1]), o);
    o = dot2f(ah[2], bch(wsu[WOH + i*4 + 2]), o);
    o = dot2f(ah[3], bch(wsu[WOH + i*4 + 3]), o);
    r[i] = xf[i] + o;
    mu += r[i];
  }
  mu *= 0.125f;
  float var = 0.f;
  #pragma unroll
  for (int i = 0; i < TT_H; ++i) { float d = r[i] - mu; var = fmaf(d, d, var); }
  float rin = __builtin_amdgcn_rsqf(fmaf(var, 0.125f, 1e-5f));
  float mc = mu * rin;
  float hr[TT_H];
  #pragma unroll
  for (int i = 0; i < TT_H; ++i)
    hr[i] = fmaf(fmaf(r[i], rin, -mc), g1[i], be1[i]);
  h2_t hh[4];
  hh[0] = pk2h(hr[0], hr[1]);
  hh[1] = pk2h(hr[2], hr[3]);
  hh[2] = pk2h(hr[4], hr[5]);
  hh[3] = pk2h(hr[6], hr[7]);

  // ---- ffn1: gelu(u) = u - u*rcp(e+1), e = 2^(u*(2.3022072 + 0.1029432*u^2)) ----
  h2_t fh[8];
  #pragma unroll
  for (int f = 0; f < TT_FF; f += 2) {
    float u0 = b1[f], u1 = b1[f+1];
    u0 = dot2f(hh[0], bch(wsu[W1H + f*4 + 0]), u0);
    u0 = dot2f(hh[1], bch(wsu[W1H + f*4 + 1]), u0);
    u0 = dot2f(hh[2], bch(wsu[W1H + f*4 + 2]), u0);
    u0 = dot2f(hh[3], bch(wsu[W1H + f*4 + 3]), u0);
    u1 = dot2f(hh[0], bch(wsu[W1H + f*4 + 4]), u1);
    u1 = dot2f(hh[1], bch(wsu[W1H + f*4 + 5]), u1);
    u1 = dot2f(hh[2], bch(wsu[W1H + f*4 + 6]), u1);
    u1 = dot2f(hh[3], bch(wsu[W1H + f*4 + 7]), u1);
    float e0 = __builtin_amdgcn_exp2f(u0 * fmaf(0.1029432f, u0*u0, 2.3022072f));
    float e1 = __builtin_amdgcn_exp2f(u1 * fmaf(0.1029432f, u1*u1, 2.3022072f));
    float g0 = fmaf(-u0, __builtin_amdgcn_rcpf(e0 + 1.0f), u0);
    float g1v = fmaf(-u1, __builtin_amdgcn_rcpf(e1 + 1.0f), u1);
    fh[f>>1] = pk2h(g0, g1v);
  }

  // ---- y = f1 @ W2.T + b2; residual; LN2; store ----
  float r2[TT_H];
  float mu2 = 0.f;
  #pragma unroll
  for (int i = 0; i < TT_H; ++i) {
    float y = b2[i];
    y = dot2f(fh[0], bch(wsu[W2H + i*8 + 0]), y);
    y = dot2f(fh[1], bch(wsu[W2H + i*8 + 1]), y);
    y = dot2f(fh[2], bch(wsu[W2H + i*8 + 2]), y);
    y = dot2f(fh[3], bch(wsu[W2H + i*8 + 3]), y);
    y = dot2f(fh[4], bch(wsu[W2H + i*8 + 4]), y);
    y = dot2f(fh[5], bch(wsu[W2H + i*8 + 5]), y);
    y = dot2f(fh[6], bch(wsu[W2H + i*8 + 6]), y);
    y = dot2f(fh[7], bch(wsu[W2H + i*8 + 7]), y);
    r2[i] = hr[i] + y;
    mu2 += r2[i];
  }
  mu2 *= 0.125f;
  float var2 = 0.f;
  #pragma unroll
  for (int i = 0; i < TT_H; ++i) { float d = r2[i] - mu2; var2 = fmaf(d, d, var2); }
  float rin2 = __builtin_amdgcn_rsqf(fmaf(var2, 0.125f, 1e-5f));
  float mc2 = mu2 * rin2;

  float res[TT_H];
  #pragma unroll
  for (int i = 0; i < TT_H; ++i)
    res[i] = fmaf(fmaf(r2[i], rin2, -mc2), g2[i], be2[i]);
  float* op = out + gidx * TT_H;
  float4 v0; v0.x = res[0]; v0.y = res[1]; v0.z = res[2]; v0.w = res[3];
  float4 v1; v1.x = res[4]; v1.y = res[5]; v1.z = res[6]; v1.w = res[7];
  ((float4*)op)[0] = v0;
  ((float4*)op)[1] = v1;
}

extern "C" void kernel_launch(void* const* d_in, const int* in_sizes, int n_in,
                              void* d_out, int out_size, void* d_ws, size_t ws_size,
                              hipStream_t stream) {
  const int*   ids = (const int*)  d_in[0];
  const float* tok = (const float*)d_in[1];
  const float* pos = (const float*)d_in[2];
  const float* Wq  = (const float*)d_in[3];
  const float* bq  = (const float*)d_in[4];
  const float* Wk  = (const float*)d_in[5];
  const float* bk  = (const float*)d_in[6];
  const float* Wv  = (const float*)d_in[7];
  const float* bv  = (const float*)d_in[8];
  const float* Wo  = (const float*)d_in[9];
  const float* bo  = (const float*)d_in[10];
  const float* W1  = (const float*)d_in[11];
  const float* b1  = (const float*)d_in[12];
  const float* W2  = (const float*)d_in[13];
  const float* b2  = (const float*)d_in[14];
  const float* g1  = (const float*)d_in[15];
  const float* be1 = (const float*)d_in[16];
  const float* g2  = (const float*)d_in[17];
  const float* be2 = (const float*)d_in[18];
  float* out = (float*)d_out;
  unsigned* ws = (unsigned*)d_ws;

  hipLaunchKernelGGL(tt_prep, dim3(1), dim3(512), 0, stream,
                     Wq, Wk, Wv, Wo, W1, W2, pos, tok, ws);

  const int B = in_sizes[0] / TT_S;
  const int grid = (B + SEQ_PER_BLK - 1) / SEQ_PER_BLK;
  hipLaunchKernelGGL(tt_fused, dim3(grid), dim3(BLK), 0, stream,
                     ids, ws, bq, bk, bv, bo, b1, b2,
                     g1, be1, g2, be2, out, B);
}

// Round 9
// 137.055 us; speedup vs baseline: 1.0514x; 1.0178x over previous
//
#include <hip/hip_runtime.h>

#define TT_S 6
#define TT_H 8
#define TT_FF 16
#define WAVES_PER_BLK 2
#define BLK (WAVES_PER_BLK * 64)      /* 128 threads */
#define SEQ_PER_WAVE 10               /* 60 active lanes, 4 idle */
#define SEQ_PER_BLK (WAVES_PER_BLK * SEQ_PER_WAVE)  /* 20 */
#define SEQ_STRIDE_U 52               /* 48 data uints + 4 pad; stride mod 32 = 20 -> <=2-way */
#define WAVE_STRIDE_U (SEQ_PER_WAVE * SEQ_STRIDE_U + 8)  /* 528 */

/* packed-fp16 layout in d_ws (uint offsets) */
#define WQH  0
#define WKH  32
#define WVH  64
#define WOH  96
#define W1H  128
#define W2H  192
#define POSH 256
#define TOKH 288    /* 400 uints */

typedef __fp16   h2_t  __attribute__((ext_vector_type(2)));
typedef _Float16 f16x2 __attribute__((ext_vector_type(2)));

__device__ __forceinline__ unsigned pk2(float a, float b) {
  h2_t h = __builtin_amdgcn_cvt_pkrtz(a, b);
  return __builtin_bit_cast(unsigned, h);
}
__device__ __forceinline__ h2_t pk2h(float a, float b) {
  return __builtin_amdgcn_cvt_pkrtz(a, b);
}
__device__ __forceinline__ h2_t bch(unsigned u) {
  return __builtin_bit_cast(h2_t, u);
}

#if __has_builtin(__builtin_amdgcn_fdot2)
__device__ __forceinline__ float dot2f(h2_t a, h2_t b, float c) {
  return __builtin_amdgcn_fdot2(__builtin_bit_cast(f16x2, a),
                                __builtin_bit_cast(f16x2, b), c, false);
}
#else
__device__ __forceinline__ float dot2f(h2_t a, h2_t b, float c) {
  return fmaf((float)a[0], (float)b[0], fmaf((float)a[1], (float)b[1], c));
}
#endif

/* ---- prep: pack weights + pos + tok_emb to fp16 pairs in ws ---- */
__global__ void tt_prep(const float* __restrict__ Wq, const float* __restrict__ Wk,
                        const float* __restrict__ Wv, const float* __restrict__ Wo,
                        const float* __restrict__ W1, const float* __restrict__ W2,
                        const float* __restrict__ pos, const float* __restrict__ tok,
                        unsigned* __restrict__ ws)
{
  const int i = threadIdx.x;  // 512 threads
  if (i < 128) {
    const float* Wm = (i < 32) ? Wq : (i < 64) ? Wk : (i < 96) ? Wv : Wo;
    const int p = i & 31;
    ws[i] = pk2(Wm[2*p], Wm[2*p+1]);
  }
  if (i < 64) {
    ws[W1H + i] = pk2(W1[2*i], W1[2*i+1]);
    ws[W2H + i] = pk2(W2[2*i], W2[2*i+1]);
  }
  if (i < 24) ws[POSH + i] = pk2(pos[2*i], pos[2*i+1]);
  if (i < 400) ws[TOKH + i] = pk2(tok[2*i], tok[2*i+1]);
}

__global__ __launch_bounds__(BLK, 8) void tt_fused(
    const int* __restrict__ ids,
    const unsigned* __restrict__ wsu,
    const float* __restrict__ bq, const float* __restrict__ bk,
    const float* __restrict__ bv, const float* __restrict__ bo,
    const float* __restrict__ b1, const float* __restrict__ b2,
    const float* __restrict__ g1, const float* __restrict__ be1,
    const float* __restrict__ g2, const float* __restrict__ be2,
    float* __restrict__ out, int B)
{
  // Per-wave KV exchange region; no __syncthreads anywhere (wave-local seqs,
  // same-wave DS ops are program-ordered).
  __shared__ __align__(16) unsigned s_kv[WAVES_PER_BLK * WAVE_STRIDE_U];

  const int tid = threadIdx.x;
  const int wv  = tid >> 6;
  const int ln  = tid & 63;
  const int slr = ln / 6;
  const int t   = ln - slr * 6;
  const int seq_g = blockIdx.x * SEQ_PER_BLK + wv * SEQ_PER_WAVE + slr;
  if (ln >= 60 || seq_g >= B) return;     // legal: no barriers below

  const size_t gidx = (size_t)seq_g * TT_S + t;
  const int id = ids[gidx];

  // ---- x row = tok(f16) + pos(f16), packed pairs ----
  uint4 tw = ((const uint4*)(wsu + TOKH))[id];
  uint4 pw = ((const uint4*)(wsu + POSH))[t];
  h2_t xs0 = bch(tw.x) + bch(pw.x);
  h2_t xs1 = bch(tw.y) + bch(pw.y);
  h2_t xs2 = bch(tw.z) + bch(pw.z);
  h2_t xs3 = bch(tw.w) + bch(pw.w);

  float xf[TT_H];
  xf[0] = (float)xs0[0]; xf[1] = (float)xs0[1];
  xf[2] = (float)xs1[0]; xf[3] = (float)xs1[1];
  xf[4] = (float)xs2[0]; xf[5] = (float)xs2[1];
  xf[6] = (float)xs3[0]; xf[7] = (float)xs3[1];

  unsigned* kvbase = s_kv + wv * WAVE_STRIDE_U + slr * SEQ_STRIDE_U;

  // ---- k,v for OWN token via dot2; pack -> wave-local LDS ----
  {
    float kr[TT_H], vr[TT_H];
    #pragma unroll
    for (int i = 0; i < TT_H; ++i) {
      float ak = bk[i], av = bv[i];
      ak = dot2f(xs0, bch(wsu[WKH + i*4 + 0]), ak);
      ak = dot2f(xs1, bch(wsu[WKH + i*4 + 1]), ak);
      ak = dot2f(xs2, bch(wsu[WKH + i*4 + 2]), ak);
      ak = dot2f(xs3, bch(wsu[WKH + i*4 + 3]), ak);
      av = dot2f(xs0, bch(wsu[WVH + i*4 + 0]), av);
      av = dot2f(xs1, bch(wsu[WVH + i*4 + 1]), av);
      av = dot2f(xs2, bch(wsu[WVH + i*4 + 2]), av);
      av = dot2f(xs3, bch(wsu[WVH + i*4 + 3]), av);
      kr[i] = ak; vr[i] = av;
    }
    unsigned* kvp = kvbase + t * 8;
    uint4 w0, w1;
    w0.x = pk2(kr[0], kr[1]); w0.y = pk2(kr[2], kr[3]);
    w0.z = pk2(kr[4], kr[5]); w0.w = pk2(kr[6], kr[7]);
    w1.x = pk2(vr[0], vr[1]); w1.y = pk2(vr[2], vr[3]);
    w1.z = pk2(vr[4], vr[5]); w1.w = pk2(vr[6], vr[7]);
    ((uint4*)kvp)[0] = w0;
    ((uint4*)kvp)[1] = w1;
  }
  __builtin_amdgcn_wave_barrier();   // scheduling fence; same-wave DS ops ordered

  // ---- q row via dot2; fold 1/sqrt(HD)*log2(e) = 0.7213475 before packing ----
  h2_t qh[4];
  #pragma unroll
  for (int i = 0; i < 4; ++i) {
    float a0 = bq[2*i], a1 = bq[2*i+1];
    a0 = dot2f(xs0, bch(wsu[WQH + (2*i)*4 + 0]), a0);
    a0 = dot2f(xs1, bch(wsu[WQH + (2*i)*4 + 1]), a0);
    a0 = dot2f(xs2, bch(wsu[WQH + (2*i)*4 + 2]), a0);
    a0 = dot2f(xs3, bch(wsu[WQH + (2*i)*4 + 3]), a0);
    a1 = dot2f(xs0, bch(wsu[WQH + (2*i+1)*4 + 0]), a1);
    a1 = dot2f(xs1, bch(wsu[WQH + (2*i+1)*4 + 1]), a1);
    a1 = dot2f(xs2, bch(wsu[WQH + (2*i+1)*4 + 2]), a1);
    a1 = dot2f(xs3, bch(wsu[WQH + (2*i+1)*4 + 3]), a1);
    qh[i] = pk2h(a0 * 0.7213475204f, a1 * 0.7213475204f);
  }

  // ---- attention: packed-fp16 V accumulation (v_pk_fma_f16) ----
  h2_t acch[4];
  acch[0] = h2_t{0.f, 0.f}; acch[1] = h2_t{0.f, 0.f};
  acch[2] = h2_t{0.f, 0.f}; acch[3] = h2_t{0.f, 0.f};
  float sum0 = 0.f, sum1 = 0.f;
  const uint4* kvb = (const uint4*)kvbase;
  #pragma unroll
  for (int t2 = 0; t2 < TT_S; ++t2) {
    uint4 kw = kvb[t2*2];
    uint4 vw = kvb[t2*2+1];
    float d0 = dot2f(qh[0], bch(kw.x), 0.f);
    d0 = dot2f(qh[1], bch(kw.y), d0);
    float d1 = dot2f(qh[2], bch(kw.z), 0.f);
    d1 = dot2f(qh[3], bch(kw.w), d1);
    float e0 = __builtin_amdgcn_exp2f(d0);
    float e1 = __builtin_amdgcn_exp2f(d1);
    sum0 += e0; sum1 += e1;
    h2_t e0p = pk2h(e0, e0);
    h2_t e1p = pk2h(e1, e1);
    acch[0] = e0p * bch(vw.x) + acch[0];
    acch[1] = e0p * bch(vw.y) + acch[1];
    acch[2] = e1p * bch(vw.z) + acch[2];
    acch[3] = e1p * bch(vw.w) + acch[3];
  }
  h2_t ah[4];
  {
    // shared rcp: 1/s0 = s1*rcp(s0*s1), 1/s1 = s0*rcp(s0*s1)
    float rs = __builtin_amdgcn_rcpf(sum0 * sum1);
    float inv0 = sum1 * rs;
    float inv1 = sum0 * rs;
    h2_t i0p = pk2h(inv0, inv0);
    h2_t i1p = pk2h(inv1, inv1);
    ah[0] = acch[0] * i0p;
    ah[1] = acch[1] * i0p;
    ah[2] = acch[2] * i1p;
    ah[3] = acch[3] * i1p;
  }

  // ---- o = attn @ Wo.T + bo; residual; LN1 ----
  float r[TT_H];
  float mu = 0.f;
  #pragma unroll
  for (int i = 0; i < TT_H; ++i) {
    float o = bo[i];
    o = dot2f(ah[0], bch(wsu[WOH + i*4 + 0]), o);
    o = dot2f(ah[1], bch(wsu[WOH + i*4 + 1]), o);
    o = dot2f(ah[2], bch(wsu[WOH + i*4 + 2]), o);
    o = dot2f(ah[3], bch(wsu[WOH + i*4 + 3]), o);
    r[i] = xf[i] + o;
    mu += r[i];
  }
  mu *= 0.125f;
  float var = 0.f;
  #pragma unroll
  for (int i = 0; i < TT_H; ++i) { float d = r[i] - mu; var = fmaf(d, d, var); }
  float rin = __builtin_amdgcn_rsqf(fmaf(var, 0.125f, 1e-5f));
  float mc = mu * rin;
  float hr[TT_H];
  #pragma unroll
  for (int i = 0; i < TT_H; ++i)
    hr[i] = fmaf(fmaf(r[i], rin, -mc), g1[i], be1[i]);
  h2_t hh[4];
  hh[0] = pk2h(hr[0], hr[1]);
  hh[1] = pk2h(hr[2], hr[3]);
  hh[2] = pk2h(hr[4], hr[5]);
  hh[3] = pk2h(hr[6], hr[7]);

  // ---- ffn1: gelu(u) = u - u*rcp(e+1), e = 2^(u*(2.3022072 + 0.1029432*u^2));
  //      one rcp per pair via shared-rcp ----
  h2_t fh[8];
  #pragma unroll
  for (int f = 0; f < TT_FF; f += 2) {
    float u0 = b1[f], u1 = b1[f+1];
    u0 = dot2f(hh[0], bch(wsu[W1H + f*4 + 0]), u0);
    u0 = dot2f(hh[1], bch(wsu[W1H + f*4 + 1]), u0);
    u0 = dot2f(hh[2], bch(wsu[W1H + f*4 + 2]), u0);
    u0 = dot2f(hh[3], bch(wsu[W1H + f*4 + 3]), u0);
    u1 = dot2f(hh[0], bch(wsu[W1H + f*4 + 4]), u1);
    u1 = dot2f(hh[1], bch(wsu[W1H + f*4 + 5]), u1);
    u1 = dot2f(hh[2], bch(wsu[W1H + f*4 + 6]), u1);
    u1 = dot2f(hh[3], bch(wsu[W1H + f*4 + 7]), u1);
    float e0 = __builtin_amdgcn_exp2f(u0 * fmaf(0.1029432f, u0*u0, 2.3022072f));
    float e1 = __builtin_amdgcn_exp2f(u1 * fmaf(0.1029432f, u1*u1, 2.3022072f));
    float a0 = e0 + 1.0f;
    float a1 = e1 + 1.0f;
    float rp = __builtin_amdgcn_rcpf(a0 * a1);
    float g0 = fmaf(-u0, a1 * rp, u0);
    float g1v = fmaf(-u1, a0 * rp, u1);
    fh[f>>1] = pk2h(g0, g1v);
  }

  // ---- y = f1 @ W2.T + b2; residual; LN2; store ----
  float r2[TT_H];
  float mu2 = 0.f;
  #pragma unroll
  for (int i = 0; i < TT_H; ++i) {
    float y = b2[i];
    y = dot2f(fh[0], bch(wsu[W2H + i*8 + 0]), y);
    y = dot2f(fh[1], bch(wsu[W2H + i*8 + 1]), y);
    y = dot2f(fh[2], bch(wsu[W2H + i*8 + 2]), y);
    y = dot2f(fh[3], bch(wsu[W2H + i*8 + 3]), y);
    y = dot2f(fh[4], bch(wsu[W2H + i*8 + 4]), y);
    y = dot2f(fh[5], bch(wsu[W2H + i*8 + 5]), y);
    y = dot2f(fh[6], bch(wsu[W2H + i*8 + 6]), y);
    y = dot2f(fh[7], bch(wsu[W2H + i*8 + 7]), y);
    r2[i] = hr[i] + y;
    mu2 += r2[i];
  }
  mu2 *= 0.125f;
  float var2 = 0.f;
  #pragma unroll
  for (int i = 0; i < TT_H; ++i) { float d = r2[i] - mu2; var2 = fmaf(d, d, var2); }
  float rin2 = __builtin_amdgcn_rsqf(fmaf(var2, 0.125f, 1e-5f));
  float mc2 = mu2 * rin2;

  float res[TT_H];
  #pragma unroll
  for (int i = 0; i < TT_H; ++i)
    res[i] = fmaf(fmaf(r2[i], rin2, -mc2), g2[i], be2[i]);
  float* op = out + gidx * TT_H;
  float4 v0; v0.x = res[0]; v0.y = res[1]; v0.z = res[2]; v0.w = res[3];
  float4 v1; v1.x = res[4]; v1.y = res[5]; v1.z = res[6]; v1.w = res[7];
  ((float4*)op)[0] = v0;
  ((float4*)op)[1] = v1;
}

extern "C" void kernel_launch(void* const* d_in, const int* in_sizes, int n_in,
                              void* d_out, int out_size, void* d_ws, size_t ws_size,
                              hipStream_t stream) {
  const int*   ids = (const int*)  d_in[0];
  const float* tok = (const float*)d_in[1];
  const float* pos = (const float*)d_in[2];
  const float* Wq  = (const float*)d_in[3];
  const float* bq  = (const float*)d_in[4];
  const float* Wk  = (const float*)d_in[5];
  const float* bk  = (const float*)d_in[6];
  const float* Wv  = (const float*)d_in[7];
  const float* bv  = (const float*)d_in[8];
  const float* Wo  = (const float*)d_in[9];
  const float* bo  = (const float*)d_in[10];
  const float* W1  = (const float*)d_in[11];
  const float* b1  = (const float*)d_in[12];
  const float* W2  = (const float*)d_in[13];
  const float* b2  = (const float*)d_in[14];
  const float* g1  = (const float*)d_in[15];
  const float* be1 = (const float*)d_in[16];
  const float* g2  = (const float*)d_in[17];
  const float* be2 = (const float*)d_in[18];
  float* out = (float*)d_out;
  unsigned* ws = (unsigned*)d_ws;

  hipLaunchKernelGGL(tt_prep, dim3(1), dim3(512), 0, stream,
                     Wq, Wk, Wv, Wo, W1, W2, pos, tok, ws);

  const int B = in_sizes[0] / TT_S;
  const int grid = (B + SEQ_PER_BLK - 1) / SEQ_PER_BLK;
  hipLaunchKernelGGL(tt_fused, dim3(grid), dim3(BLK), 0, stream,
                     ids, ws, bq, bk, bv, bo, b1, b2,
                     g1, be1, g2, be2, out, B);
}